// Round 11
// baseline (136.792 us; speedup 1.0000x reference)
//
#include <hip/hip_runtime.h>
#include <math.h>

#define R_ROUTES 1152
#define CIN 8
#define COUT 16
#define BATCH 512
#define NCAPS 10
#define NUM_ROUNDS 3

#define WP_U32S (NCAPS * R_ROUTES * COUT * 4)            // 737,280 u32 = 2,949,120 B
#define XP_U32S (BATCH * R_ROUTES * 4)                   // 2,359,296 u32 = 9,437,184 B
#define WS_NEED ((size_t)(WP_U32S + XP_U32S) * 4)        // 12,386,304 B

typedef __fp16 h2 __attribute__((ext_vector_type(2)));
union U32H2 { unsigned int u; h2 h; };

__device__ __forceinline__ unsigned int pkrtz(float lo, float hi) {
    U32H2 v; v.h = __builtin_amdgcn_cvt_pkrtz(lo, hi);   // v_cvt_pkrtz_f16_f32
    return v.u;
}
__device__ __forceinline__ h2 as_h2(unsigned int u) { U32H2 v; v.u = u; return v.h; }
__device__ __forceinline__ float f_lo(unsigned int u) { return (float)as_h2(u).x; }
__device__ __forceinline__ float f_hi(unsigned int u) { return (float)as_h2(u).y; }
__device__ __forceinline__ float dot2(unsigned int p, unsigned int s, float c) {
    return __builtin_amdgcn_fdot2(as_h2(p), as_h2(s), c, false);  // v_dot2_f32_f16
}

// Swizzled 16-B-unit index for (row r, half h): bijection within each 128-B
// group, spreads consecutive-r b128 reads over all 8 bank groups (R5-verified).
__device__ __forceinline__ int sunit(int r, int h) {
    return (2 * r + h) ^ ((r >> 2) & 7);
}

// ---------------- pack kernel: W fp32 -> Wp f16-pairs [n][r][o][i/2],
// and (blocks >= 720) x fp32 -> xp f16-pairs [b][r][i/2].
extern "C" __global__ void __launch_bounds__(256)
pack_wx(const float* __restrict__ W, const float* __restrict__ x,
        unsigned int* __restrict__ Wp, unsigned int* __restrict__ xp)
{
    const int bid = blockIdx.x;
    if (bid < NCAPS * R_ROUTES * COUT / 256) {           // 720 blocks: W
        const int tau = bid * 256 + threadIdx.x;         // (n*1152+r)*16 + o
        const int o = tau & 15;
        const int nr = tau >> 4;
        const float* __restrict__ src = W + (size_t)nr * 128 + o;
        uint4 u;
        u.x = pkrtz(src[0],  src[16]);
        u.y = pkrtz(src[32], src[48]);
        u.z = pkrtz(src[64], src[80]);
        u.w = pkrtz(src[96], src[112]);
        *(uint4*)(Wp + (size_t)tau * 4) = u;
    } else {                                             // 2304 blocks: x
        const int idx = (bid - NCAPS * R_ROUTES * COUT / 256) * 256 + threadIdx.x;
        const float4 v0 = *(const float4*)(x + (size_t)idx * 8);
        const float4 v1 = *(const float4*)(x + (size_t)idx * 8 + 4);
        uint4 u;
        u.x = pkrtz(v0.x, v0.y); u.y = pkrtz(v0.z, v0.w);
        u.z = pkrtz(v1.x, v1.y); u.w = pkrtz(v1.z, v1.w);
        *(uint4*)(xp + (size_t)idx * 4) = u;
    }
}

#define LOADS(IT, W0, W1, W2, W3, XA, XB)                                  \
    {                                                                      \
        const int r_ = (IT) * 128 + q;                                     \
        const unsigned int* __restrict__ wb_ = Wn + (size_t)r_ * 64 + oq * 4; \
        W0 = *(const uint4*)(wb_);                                         \
        W1 = *(const uint4*)(wb_ + 16);                                    \
        W2 = *(const uint4*)(wb_ + 32);                                    \
        W3 = *(const uint4*)(wb_ + 48);                                    \
        XA = *(const uint4*)(xp0 + (size_t)r_ * 4);                        \
        XB = *(const uint4*)(xp1 + (size_t)r_ * 4);                        \
    }

#define COMPUTES(IT, W0, W1, W2, W3, XA, XB)                               \
    {                                                                      \
        const int r_ = (IT) * 128 + q;                                     \
        {                                                                  \
            const float p0 = dot2(W0.w, XA.w, dot2(W0.z, XA.z, dot2(W0.y, XA.y, dot2(W0.x, XA.x, 0.f)))); \
            const float p1 = dot2(W1.w, XA.w, dot2(W1.z, XA.z, dot2(W1.y, XA.y, dot2(W1.x, XA.x, 0.f)))); \
            const float p2 = dot2(W2.w, XA.w, dot2(W2.z, XA.z, dot2(W2.y, XA.y, dot2(W2.x, XA.x, 0.f)))); \
            const float p3 = dot2(W3.w, XA.w, dot2(W3.z, XA.z, dot2(W3.y, XA.y, dot2(W3.x, XA.x, 0.f)))); \
            cs00 += p0; cs01 += p1; cs02 += p2; cs03 += p3;                \
            uint2 u_; u_.x = pkrtz(p0, p1); u_.y = pkrtz(p2, p3);          \
            *(uint2*)(pbuf + sunit(r_, hq) * 4 + subw) = u_;               \
        }                                                                  \
        {                                                                  \
            const float p0 = dot2(W0.w, XB.w, dot2(W0.z, XB.z, dot2(W0.y, XB.y, dot2(W0.x, XB.x, 0.f)))); \
            const float p1 = dot2(W1.w, XB.w, dot2(W1.z, XB.z, dot2(W1.y, XB.y, dot2(W1.x, XB.x, 0.f)))); \
            const float p2 = dot2(W2.w, XB.w, dot2(W2.z, XB.z, dot2(W2.y, XB.y, dot2(W2.x, XB.x, 0.f)))); \
            const float p3 = dot2(W3.w, XB.w, dot2(W3.z, XB.z, dot2(W3.y, XB.y, dot2(W3.x, XB.x, 0.f)))); \
            cs10 += p0; cs11 += p1; cs12 += p2; cs13 += p3;                \
            uint2 u_; u_.x = pkrtz(p0, p1); u_.y = pkrtz(p2, p3);          \
            *(uint2*)(pbuf + R_ROUTES * 8 + sunit(r_, hq) * 4 + subw) = u_; \
        }                                                                  \
    }

// ---------------- Main: 512 threads per (n, b-pair), all-f16 inputs.
// Phase A: 2-stage software pipeline (double-buffered W/x regs, static
// names -> no dynamic indexing -> no scratch). Pass-0 colsums fused in.
// Phase B: 2 fused passes (R10-verified). LDS ~80 KB -> 2 blocks/CU.
extern "C" __global__ void __launch_bounds__(512, 4)
capsule_routing_v10(const unsigned int* __restrict__ xp,
                    const unsigned int* __restrict__ Wp,
                    float* __restrict__ out)
{
    __shared__ unsigned int pbuf[2 * R_ROUTES * 8];  // 73728 B f16 priors (swizzled)
    __shared__ float wred[16 * 16];                  // 1024 B pass-0 wave sums
    __shared__ float red[2 * 32 * 20];               // 5120 B pass-reduction scratch
    __shared__ float sred[2 * 4];                    // per-wave exp sums
    __shared__ float sv[2 * 16];                     // s vectors (permuted order)

    const int blk = blockIdx.x;                      // n-major: Wp[n] L2-resident
    const int n = blk >> 8;
    const int bp = blk & 255;
    const int t = threadIdx.x;

    const unsigned int* __restrict__ xp0 = xp + (size_t)(2 * bp) * (R_ROUTES * 4);
    const unsigned int* __restrict__ xp1 = xp0 + R_ROUTES * 4;
    const unsigned int* __restrict__ Wn = Wp + (size_t)n * (R_ROUTES * 64);

    // ---------------- Phase A: pipelined priors (dot2) + pass-0 colsums
    float cs00 = 0.f, cs01 = 0.f, cs02 = 0.f, cs03 = 0.f;
    float cs10 = 0.f, cs11 = 0.f, cs12 = 0.f, cs13 = 0.f;
    {
        const int q = t >> 2;                        // 0..127
        const int oq = t & 3;
        const int subw = (oq & 1) * 2;
        const int hq = oq >> 1;

        uint4 wA0, wA1, wA2, wA3, xAa, xAb;          // stage A
        uint4 wB0, wB1, wB2, wB3, xBa, xBb;          // stage B

        LOADS(0, wA0, wA1, wA2, wA3, xAa, xAb);
        #pragma unroll 1
        for (int it = 0; it < 8; it += 2) {
            LOADS(it + 1, wB0, wB1, wB2, wB3, xBa, xBb);
            COMPUTES(it, wA0, wA1, wA2, wA3, xAa, xAb);
            LOADS(it + 2, wA0, wA1, wA2, wA3, xAa, xAb);   // it+2 <= 8 always
            COMPUTES(it + 1, wB0, wB1, wB2, wB3, xBa, xBb);
        }
        COMPUTES(8, wA0, wA1, wA2, wA3, xAa, xAb);

        // pass-0 reduce: butterfly over same-oq lanes (masks 4..32)
        #pragma unroll
        for (int mask = 4; mask <= 32; mask <<= 1) {
            cs00 += __shfl_xor(cs00, mask, 64); cs01 += __shfl_xor(cs01, mask, 64);
            cs02 += __shfl_xor(cs02, mask, 64); cs03 += __shfl_xor(cs03, mask, 64);
            cs10 += __shfl_xor(cs10, mask, 64); cs11 += __shfl_xor(cs11, mask, 64);
            cs12 += __shfl_xor(cs12, mask, 64); cs13 += __shfl_xor(cs13, mask, 64);
        }
        if ((t & 63) < 4) {                          // lane oq of each wave writes
            const int w = t >> 6;
            *(float4*)(wred + (w * 2 + 0) * 16 + 4 * oq) = make_float4(cs00, cs01, cs02, cs03);
            *(float4*)(wred + (w * 2 + 1) * 16 + 4 * oq) = make_float4(cs10, cs11, cs12, cs13);
        }
    }
    __syncthreads();                                 // barA1 (pbuf + wred ready)

    // ---------------- Phase B (R10-verified, permuted column order P)
    const int half = t >> 8;
    const int tt = t & 255;
    unsigned int* __restrict__ pb = pbuf + half * (R_ROUTES * 8);
    float* __restrict__ redh = red + half * (32 * 20);
    float* __restrict__ sredh = sred + half * 4;
    float* __restrict__ svh = sv + half * 16;

    if (tt < 16) {
        float s = 0.f;
        #pragma unroll
        for (int w = 0; w < 8; ++w) s += wred[(w * 2 + half) * 16 + tt];
        svh[tt] = s * (1.0f / (float)R_ROUTES);
    }
    __syncthreads();                                 // barA2

    float sn = 0.f;
    #pragma unroll
    for (int o = 0; o < 16; ++o) { const float s = svh[o]; sn = fmaf(s, s, sn); }
    float factor = sn / ((1.0f + sn) * sqrtf(sn));

    const int nr = (tt < 128) ? 5 : 4;               // wave-uniform
    float bl[5] = {0.f, 0.f, 0.f, 0.f, 0.f};

    #pragma unroll 1
    for (int pass = 1; pass < NUM_ROUNDS; ++pass) {
        unsigned int svp[8];
        #pragma unroll
        for (int s = 0; s < 8; ++s)
            svp[s] = pkrtz(svh[2 * s], svh[2 * s + 1]);
        float acc[16];
        #pragma unroll
        for (int o = 0; o < 16; ++o) acc[o] = 0.f;
        float es = 0.f;

        #pragma unroll
        for (int k = 0; k < 5; ++k) {
            if (k < nr) {
                const int r = tt + (k << 8);
                const uint4 a = *(const uint4*)(pb + sunit(r, 0) * 4);
                const uint4 c = *(const uint4*)(pb + sunit(r, 1) * 4);
                float d = 0.f;
                d = dot2(a.x, svp[0], d);
                d = dot2(a.y, svp[1], d);
                d = dot2(a.z, svp[2], d);
                d = dot2(a.w, svp[3], d);
                d = dot2(c.x, svp[4], d);
                d = dot2(c.y, svp[5], d);
                d = dot2(c.z, svp[6], d);
                d = dot2(c.w, svp[7], d);
                bl[k] = fmaf(factor, d, bl[k]);
                const float e = __expf(bl[k]);
                es += e;
                acc[0]  = fmaf(e, f_lo(a.x), acc[0]);
                acc[1]  = fmaf(e, f_hi(a.x), acc[1]);
                acc[2]  = fmaf(e, f_lo(a.y), acc[2]);
                acc[3]  = fmaf(e, f_hi(a.y), acc[3]);
                acc[4]  = fmaf(e, f_lo(a.z), acc[4]);
                acc[5]  = fmaf(e, f_hi(a.z), acc[5]);
                acc[6]  = fmaf(e, f_lo(a.w), acc[6]);
                acc[7]  = fmaf(e, f_hi(a.w), acc[7]);
                acc[8]  = fmaf(e, f_lo(c.x), acc[8]);
                acc[9]  = fmaf(e, f_hi(c.x), acc[9]);
                acc[10] = fmaf(e, f_lo(c.y), acc[10]);
                acc[11] = fmaf(e, f_hi(c.y), acc[11]);
                acc[12] = fmaf(e, f_lo(c.z), acc[12]);
                acc[13] = fmaf(e, f_hi(c.z), acc[13]);
                acc[14] = fmaf(e, f_lo(c.w), acc[14]);
                acc[15] = fmaf(e, f_hi(c.w), acc[15]);
            }
        }
        #pragma unroll
        for (int off = 32; off > 0; off >>= 1) es += __shfl_xor(es, off, 64);
        if ((t & 63) == 0) sredh[tt >> 6] = es;

        #pragma unroll
        for (int o = 0; o < 16; ++o) {
            acc[o] += __shfl_xor(acc[o], 1, 64);
            acc[o] += __shfl_xor(acc[o], 2, 64);
            acc[o] += __shfl_xor(acc[o], 4, 64);
        }
        if ((tt & 7) == 0) {
            float* dst = redh + (tt >> 3) * 20;      // 80-B stride: conflict-free b128
            *(float4*)(dst + 0)  = make_float4(acc[0],  acc[1],  acc[2],  acc[3]);
            *(float4*)(dst + 4)  = make_float4(acc[4],  acc[5],  acc[6],  acc[7]);
            *(float4*)(dst + 8)  = make_float4(acc[8],  acc[9],  acc[10], acc[11]);
            *(float4*)(dst + 12) = make_float4(acc[12], acc[13], acc[14], acc[15]);
        }
        __syncthreads();                             // bar1

        if (tt < 16) {
            float s = 0.f;
            #pragma unroll
            for (int w = 0; w < 32; ++w) s += redh[w * 20 + tt];
            const float Z = sredh[0] + sredh[1] + sredh[2] + sredh[3];
            svh[tt] = s / Z;
        }
        __syncthreads();                             // bar2

        sn = 0.f;
        #pragma unroll
        for (int o = 0; o < 16; ++o) { const float s = svh[o]; sn = fmaf(s, s, sn); }
        factor = sn / ((1.0f + sn) * sqrtf(sn));
    }

    if (tt < 16) {
        const int o = (tt >> 2) + ((tt & 3) << 2);   // un-permute P[tt]
        out[((size_t)n * BATCH + 2 * bp + half) * COUT + o] = factor * svh[tt];
    }
}

// ---------------- Fallback (ws too small for xp): exact R10 pipeline-free
// kernel reading x fp32 directly + packing per-iteration.
extern "C" __global__ void __launch_bounds__(256)
pack_w_only(const float* __restrict__ W, unsigned int* __restrict__ Wp)
{
    const int tau = blockIdx.x * 256 + threadIdx.x;
    const int o = tau & 15;
    const int nr = tau >> 4;
    const float* __restrict__ src = W + (size_t)nr * 128 + o;
    uint4 u;
    u.x = pkrtz(src[0],  src[16]);
    u.y = pkrtz(src[32], src[48]);
    u.z = pkrtz(src[64], src[80]);
    u.w = pkrtz(src[96], src[112]);
    *(uint4*)(Wp + (size_t)tau * 4) = u;
}

extern "C" __global__ void __launch_bounds__(512, 4)
capsule_routing_v9f(const float* __restrict__ x,
                    const unsigned int* __restrict__ Wp,
                    float* __restrict__ out)
{
    __shared__ unsigned int pbuf[2 * R_ROUTES * 8];
    __shared__ float wred[16 * 16];
    __shared__ float red[2 * 32 * 20];
    __shared__ float sred[2 * 4];
    __shared__ float sv[2 * 16];

    const int blk = blockIdx.x;
    const int n = blk >> 8;
    const int bp = blk & 255;
    const int t = threadIdx.x;

    const float* __restrict__ x0 = x + (size_t)(2 * bp) * (R_ROUTES * CIN);
    const float* __restrict__ x1 = x0 + R_ROUTES * CIN;
    const unsigned int* __restrict__ Wn = Wp + (size_t)n * (R_ROUTES * 64);

    float cs00 = 0.f, cs01 = 0.f, cs02 = 0.f, cs03 = 0.f;
    float cs10 = 0.f, cs11 = 0.f, cs12 = 0.f, cs13 = 0.f;
    {
        const int q = t >> 2;
        const int oq = t & 3;
        const int subw = (oq & 1) * 2;
        const int hq = oq >> 1;

        #pragma unroll 1
        for (int it = 0; it < 9; ++it) {
            const int r = it * 128 + q;
            const unsigned int* __restrict__ wb = Wn + (size_t)r * 64 + oq * 4;
            const uint4 w0 = *(const uint4*)(wb);
            const uint4 w1 = *(const uint4*)(wb + 16);
            const uint4 w2 = *(const uint4*)(wb + 32);
            const uint4 w3 = *(const uint4*)(wb + 48);
            const float4 xa0 = *(const float4*)(x0 + r * 8);
            const float4 xa1 = *(const float4*)(x0 + r * 8 + 4);
            const float4 xb0 = *(const float4*)(x1 + r * 8);
            const float4 xb1 = *(const float4*)(x1 + r * 8 + 4);
            {
                const unsigned int xq0 = pkrtz(xa0.x, xa0.y), xq1 = pkrtz(xa0.z, xa0.w);
                const unsigned int xq2 = pkrtz(xa1.x, xa1.y), xq3 = pkrtz(xa1.z, xa1.w);
                const float p0 = dot2(w0.w, xq3, dot2(w0.z, xq2, dot2(w0.y, xq1, dot2(w0.x, xq0, 0.f))));
                const float p1 = dot2(w1.w, xq3, dot2(w1.z, xq2, dot2(w1.y, xq1, dot2(w1.x, xq0, 0.f))));
                const float p2 = dot2(w2.w, xq3, dot2(w2.z, xq2, dot2(w2.y, xq1, dot2(w2.x, xq0, 0.f))));
                const float p3 = dot2(w3.w, xq3, dot2(w3.z, xq2, dot2(w3.y, xq1, dot2(w3.x, xq0, 0.f))));
                cs00 += p0; cs01 += p1; cs02 += p2; cs03 += p3;
                uint2 u; u.x = pkrtz(p0, p1); u.y = pkrtz(p2, p3);
                *(uint2*)(pbuf + sunit(r, hq) * 4 + subw) = u;
            }
            {
                const unsigned int xq0 = pkrtz(xb0.x, xb0.y), xq1 = pkrtz(xb0.z, xb0.w);
                const unsigned int xq2 = pkrtz(xb1.x, xb1.y), xq3 = pkrtz(xb1.z, xb1.w);
                const float p0 = dot2(w0.w, xq3, dot2(w0.z, xq2, dot2(w0.y, xq1, dot2(w0.x, xq0, 0.f))));
                const float p1 = dot2(w1.w, xq3, dot2(w1.z, xq2, dot2(w1.y, xq1, dot2(w1.x, xq0, 0.f))));
                const float p2 = dot2(w2.w, xq3, dot2(w2.z, xq2, dot2(w2.y, xq1, dot2(w2.x, xq0, 0.f))));
                const float p3 = dot2(w3.w, xq3, dot2(w3.z, xq2, dot2(w3.y, xq1, dot2(w3.x, xq0, 0.f))));
                cs10 += p0; cs11 += p1; cs12 += p2; cs13 += p3;
                uint2 u; u.x = pkrtz(p0, p1); u.y = pkrtz(p2, p3);
                *(uint2*)(pbuf + R_ROUTES * 8 + sunit(r, hq) * 4 + subw) = u;
            }
        }
        #pragma unroll
        for (int mask = 4; mask <= 32; mask <<= 1) {
            cs00 += __shfl_xor(cs00, mask, 64); cs01 += __shfl_xor(cs01, mask, 64);
            cs02 += __shfl_xor(cs02, mask, 64); cs03 += __shfl_xor(cs03, mask, 64);
            cs10 += __shfl_xor(cs10, mask, 64); cs11 += __shfl_xor(cs11, mask, 64);
            cs12 += __shfl_xor(cs12, mask, 64); cs13 += __shfl_xor(cs13, mask, 64);
        }
        if ((t & 63) < 4) {
            const int w = t >> 6;
            *(float4*)(wred + (w * 2 + 0) * 16 + 4 * oq) = make_float4(cs00, cs01, cs02, cs03);
            *(float4*)(wred + (w * 2 + 1) * 16 + 4 * oq) = make_float4(cs10, cs11, cs12, cs13);
        }
    }
    __syncthreads();

    const int half = t >> 8;
    const int tt = t & 255;
    unsigned int* __restrict__ pb = pbuf + half * (R_ROUTES * 8);
    float* __restrict__ redh = red + half * (32 * 20);
    float* __restrict__ sredh = sred + half * 4;
    float* __restrict__ svh = sv + half * 16;

    if (tt < 16) {
        float s = 0.f;
        #pragma unroll
        for (int w = 0; w < 8; ++w) s += wred[(w * 2 + half) * 16 + tt];
        svh[tt] = s * (1.0f / (float)R_ROUTES);
    }
    __syncthreads();

    float sn = 0.f;
    #pragma unroll
    for (int o = 0; o < 16; ++o) { const float s = svh[o]; sn = fmaf(s, s, sn); }
    float factor = sn / ((1.0f + sn) * sqrtf(sn));

    const int nr = (tt < 128) ? 5 : 4;
    float bl[5] = {0.f, 0.f, 0.f, 0.f, 0.f};

    #pragma unroll 1
    for (int pass = 1; pass < NUM_ROUNDS; ++pass) {
        unsigned int svp[8];
        #pragma unroll
        for (int s = 0; s < 8; ++s) svp[s] = pkrtz(svh[2 * s], svh[2 * s + 1]);
        float acc[16];
        #pragma unroll
        for (int o = 0; o < 16; ++o) acc[o] = 0.f;
        float es = 0.f;
        #pragma unroll
        for (int k = 0; k < 5; ++k) {
            if (k < nr) {
                const int r = tt + (k << 8);
                const uint4 a = *(const uint4*)(pb + sunit(r, 0) * 4);
                const uint4 c = *(const uint4*)(pb + sunit(r, 1) * 4);
                float d = 0.f;
                d = dot2(a.x, svp[0], d); d = dot2(a.y, svp[1], d);
                d = dot2(a.z, svp[2], d); d = dot2(a.w, svp[3], d);
                d = dot2(c.x, svp[4], d); d = dot2(c.y, svp[5], d);
                d = dot2(c.z, svp[6], d); d = dot2(c.w, svp[7], d);
                bl[k] = fmaf(factor, d, bl[k]);
                const float e = __expf(bl[k]);
                es += e;
                acc[0]  = fmaf(e, f_lo(a.x), acc[0]);  acc[1]  = fmaf(e, f_hi(a.x), acc[1]);
                acc[2]  = fmaf(e, f_lo(a.y), acc[2]);  acc[3]  = fmaf(e, f_hi(a.y), acc[3]);
                acc[4]  = fmaf(e, f_lo(a.z), acc[4]);  acc[5]  = fmaf(e, f_hi(a.z), acc[5]);
                acc[6]  = fmaf(e, f_lo(a.w), acc[6]);  acc[7]  = fmaf(e, f_hi(a.w), acc[7]);
                acc[8]  = fmaf(e, f_lo(c.x), acc[8]);  acc[9]  = fmaf(e, f_hi(c.x), acc[9]);
                acc[10] = fmaf(e, f_lo(c.y), acc[10]); acc[11] = fmaf(e, f_hi(c.y), acc[11]);
                acc[12] = fmaf(e, f_lo(c.z), acc[12]); acc[13] = fmaf(e, f_hi(c.z), acc[13]);
                acc[14] = fmaf(e, f_lo(c.w), acc[14]); acc[15] = fmaf(e, f_hi(c.w), acc[15]);
            }
        }
        #pragma unroll
        for (int off = 32; off > 0; off >>= 1) es += __shfl_xor(es, off, 64);
        if ((t & 63) == 0) sredh[tt >> 6] = es;
        #pragma unroll
        for (int o = 0; o < 16; ++o) {
            acc[o] += __shfl_xor(acc[o], 1, 64);
            acc[o] += __shfl_xor(acc[o], 2, 64);
            acc[o] += __shfl_xor(acc[o], 4, 64);
        }
        if ((tt & 7) == 0) {
            float* dst = redh + (tt >> 3) * 20;
            *(float4*)(dst + 0)  = make_float4(acc[0],  acc[1],  acc[2],  acc[3]);
            *(float4*)(dst + 4)  = make_float4(acc[4],  acc[5],  acc[6],  acc[7]);
            *(float4*)(dst + 8)  = make_float4(acc[8],  acc[9],  acc[10], acc[11]);
            *(float4*)(dst + 12) = make_float4(acc[12], acc[13], acc[14], acc[15]);
        }
        __syncthreads();
        if (tt < 16) {
            float s = 0.f;
            #pragma unroll
            for (int w = 0; w < 32; ++w) s += redh[w * 20 + tt];
            const float Z = sredh[0] + sredh[1] + sredh[2] + sredh[3];
            svh[tt] = s / Z;
        }
        __syncthreads();
        sn = 0.f;
        #pragma unroll
        for (int o = 0; o < 16; ++o) { const float s = svh[o]; sn = fmaf(s, s, sn); }
        factor = sn / ((1.0f + sn) * sqrtf(sn));
    }

    if (tt < 16) {
        const int o = (tt >> 2) + ((tt & 3) << 2);
        out[((size_t)n * BATCH + 2 * bp + half) * COUT + o] = factor * svh[tt];
    }
}

extern "C" void kernel_launch(void* const* d_in, const int* in_sizes, int n_in,
                              void* d_out, int out_size, void* d_ws, size_t ws_size,
                              hipStream_t stream) {
    const float* x = (const float*)d_in[0];   // [512, 1152, 8] fp32
    const float* W = (const float*)d_in[1];   // [10, 1152, 8, 16] fp32
    float* out = (float*)d_out;               // [10, 512, 1, 1, 16] fp32
    unsigned int* Wp = (unsigned int*)d_ws;
    unsigned int* xp = Wp + WP_U32S;

    if (ws_size >= WS_NEED) {
        const int wblocks = NCAPS * R_ROUTES * COUT / 256;          // 720
        const int xblocks = BATCH * R_ROUTES / 256;                 // 2304
        pack_wx<<<dim3(wblocks + xblocks), dim3(256), 0, stream>>>(W, x, Wp, xp);
        capsule_routing_v10<<<dim3(NCAPS * (BATCH / 2)), dim3(512), 0, stream>>>(xp, Wp, out);
    } else {
        pack_w_only<<<dim3(NCAPS * R_ROUTES * COUT / 256), dim3(256), 0, stream>>>(W, Wp);
        capsule_routing_v9f<<<dim3(NCAPS * (BATCH / 2)), dim3(512), 0, stream>>>(x, Wp, out);
    }
}